// Round 2
// baseline (646.248 us; speedup 1.0000x reference)
//
#include <hip/hip_runtime.h>
#include <stdint.h>

namespace {

constexpr int kBH = 128;
constexpr int kS  = 1024;
constexpr int kD  = 64;
constexpr int kQB = 32;
constexpr int kStride = kS + 4;                  // f32 LDS stride: 2-way banks (free), 16B aligned
constexpr float kScale = 0.04419417382415922f;   // 1/sqrt(512)  (temper = sqrt(d_model))
constexpr float kNegInf = -3.0e38f;

typedef __attribute__((ext_vector_type(8))) short short8;  // 8 bf16 (4 VGPRs)
typedef __attribute__((ext_vector_type(4))) float f32x4;
typedef __attribute__((ext_vector_type(4))) int   i32x4;

__device__ inline short f2bf(float f) {          // f32 -> bf16 bits, RNE
    union { float f; uint32_t u; } x; x.f = f;
    uint32_t r = x.u + 0x7fffu + ((x.u >> 16) & 1u);
    return (short)(r >> 16);
}

__global__ __launch_bounds__(512)
void sdpa_kernel(const float* __restrict__ Q, const float* __restrict__ K,
                 const float* __restrict__ V, const int* __restrict__ M,
                 float* __restrict__ Og, float* __restrict__ Ag) {
    __shared__ float s_lds[kQB * kStride];       // 131,584 B raw scores -> exp(p)
    __shared__ float inv_lds[kQB];

    // XCD-aware swizzle: 4096 WGs, 8 XCDs -> 512 consecutive logical WGs per XCD,
    // so each bh's 32 q-tiles share one XCD's L2 (K+V = 512 KB resident).
    const int logical = (blockIdx.x & 7) * 512 + (blockIdx.x >> 3);
    const int bh = logical >> 5;
    const int q0 = (logical & 31) * kQB;

    const int tid  = threadIdx.x;
    const int wave = tid >> 6;
    const int lane = tid & 63;
    const int l16  = lane & 15;
    const int lg   = lane >> 4;

    const float* qb = Q + (size_t)bh * kS * kD;
    const float* kb = K + (size_t)bh * kS * kD;
    const float* vb = V + (size_t)bh * kS * kD;

    // ---- Q fragments (2 m-tiles x 2 k-steps), A[row=l16][k=lg*8+j] ----
    short8 afr[2][2];
    #pragma unroll
    for (int m = 0; m < 2; ++m)
    #pragma unroll
    for (int ks = 0; ks < 2; ++ks) {
        const float* p = qb + (size_t)(q0 + m * 16 + l16) * kD + ks * 32 + lg * 8;
        short8 t;
        #pragma unroll
        for (int j = 0; j < 8; ++j) t[j] = f2bf(p[j]);
        afr[m][ks] = t;
    }

    // ---- Phase 1: raw QK^T scores -> LDS; wave owns 128-col slice ----
    const int n0 = wave * 128;
    for (int nt = 0; nt < 8; ++nt) {
        const int nb = n0 + nt * 16;
        short8 bfr[2];
        #pragma unroll
        for (int ks = 0; ks < 2; ++ks) {
            const float* p = kb + (size_t)(nb + l16) * kD + ks * 32 + lg * 8;
            short8 t;
            #pragma unroll
            for (int j = 0; j < 8; ++j) t[j] = f2bf(p[j]);
            bfr[ks] = t;
        }
        #pragma unroll
        for (int m = 0; m < 2; ++m) {
            f32x4 acc = {0.f, 0.f, 0.f, 0.f};
            acc = __builtin_amdgcn_mfma_f32_16x16x32_bf16(afr[m][0], bfr[0], acc, 0, 0, 0);
            acc = __builtin_amdgcn_mfma_f32_16x16x32_bf16(afr[m][1], bfr[1], acc, 0, 0, 0);
            const int rbase = m * 16 + lg * 4;   // C/D: col=lane&15, row=(lane>>4)*4+r
            #pragma unroll
            for (int r = 0; r < 4; ++r)
                s_lds[(rbase + r) * kStride + nb + l16] = acc[r];
        }
    }
    __syncthreads();

    // ---- Phase 2: mask+scale -> rowmax -> exp -> rowsum -> attn write ----
    {
        const int row = tid >> 4;                // 32 rows x 16 threads
        const int c0  = (tid & 15) * 4;
        const int* mrow = M + ((size_t)bh * kS + q0 + row) * kS;
        float* srow = s_lds + row * kStride;

        float mx = kNegInf;
        #pragma unroll
        for (int i = 0; i < 16; ++i) {
            const int c = c0 + i * 64;           // int4/float4, 256B coalesced per 16 threads
            i32x4 mk = *(const i32x4*)(mrow + c);
            f32x4 s  = *(const f32x4*)(srow + c);
            f32x4 e;
            e.x = mk.x ? kNegInf : s.x * kScale;
            e.y = mk.y ? kNegInf : s.y * kScale;
            e.z = mk.z ? kNegInf : s.z * kScale;
            e.w = mk.w ? kNegInf : s.w * kScale;
            *(f32x4*)(srow + c) = e;
            mx = fmaxf(mx, fmaxf(fmaxf(e.x, e.y), fmaxf(e.z, e.w)));
        }
        #pragma unroll
        for (int o = 8; o; o >>= 1) mx = fmaxf(mx, __shfl_xor(mx, o));

        float sum = 0.f;
        #pragma unroll
        for (int i = 0; i < 16; ++i) {
            const int c = c0 + i * 64;
            f32x4 s = *(const f32x4*)(srow + c);
            f32x4 p;
            p.x = __expf(s.x - mx);
            p.y = __expf(s.y - mx);
            p.z = __expf(s.z - mx);
            p.w = __expf(s.w - mx);
            *(f32x4*)(srow + c) = p;             // keep UNNORMALIZED p in LDS
            sum += (p.x + p.y) + (p.z + p.w);
        }
        #pragma unroll
        for (int o = 8; o; o >>= 1) sum += __shfl_xor(sum, o);
        const float inv = 1.0f / sum;
        if ((tid & 15) == 0) inv_lds[row] = inv;

        float* arow = Ag + ((size_t)bh * kS + q0 + row) * kS;
        #pragma unroll
        for (int i = 0; i < 16; ++i) {
            const int c = c0 + i * 64;
            f32x4 p = *(const f32x4*)(srow + c);
            f32x4 a = p * inv;
            *(f32x4*)(arow + c) = a;             // coalesced float4 attn store
        }
    }
    __syncthreads();

    // ---- Phase 3: O = (P*inv) @ V; wave -> one 16x16 output tile, full K=1024 ----
    {
        const int m  = wave >> 2;                // 0..1
        const int d0 = (wave & 3) * 16;          // 0..48
        const float invr = inv_lds[m * 16 + l16];
        const float* pa0 = s_lds + (size_t)(m * 16 + l16) * kStride + lg * 8;
        f32x4 acc = {0.f, 0.f, 0.f, 0.f};
        for (int ks = 0; ks < 32; ++ks) {
            short8 a;                            // A[row=l16][k=ks*32+lg*8+j]
            const float* pa = pa0 + ks * 32;
            #pragma unroll
            for (int j = 0; j < 8; ++j) a[j] = f2bf(pa[j] * invr);
            short8 b;                            // B[k][n=d0+l16] = V[k][d]
            const float* pv = vb + (size_t)(ks * 32 + lg * 8) * kD + d0 + l16;
            #pragma unroll
            for (int j = 0; j < 8; ++j) b[j] = f2bf(pv[(size_t)j * kD]);
            acc = __builtin_amdgcn_mfma_f32_16x16x32_bf16(a, b, acc, 0, 0, 0);
        }
        float* orow = Og + ((size_t)bh * kS + q0 + m * 16 + lg * 4) * kD + d0 + l16;
        #pragma unroll
        for (int r = 0; r < 4; ++r) orow[(size_t)r * kD] = acc[r];
    }
}

} // namespace

extern "C" void kernel_launch(void* const* d_in, const int* in_sizes, int n_in,
                              void* d_out, int out_size, void* d_ws, size_t ws_size,
                              hipStream_t stream) {
    const float* q = (const float*)d_in[0];
    const float* k = (const float*)d_in[1];
    const float* v = (const float*)d_in[2];
    const int*   m = (const int*)d_in[3];
    float* og = (float*)d_out;
    float* ag = og + (size_t)kBH * kS * kD;      // outputs concatenated: O then attn
    sdpa_kernel<<<dim3(kBH * (kS / kQB)), dim3(512), 0, stream>>>(q, k, v, m, og, ag);
}

// Round 3
// 392.315 us; speedup vs baseline: 1.6473x; 1.6473x over previous
//
#include <hip/hip_runtime.h>
#include <stdint.h>

namespace {

constexpr int kBH = 128;
constexpr int kS  = 1024;
constexpr int kD  = 64;
constexpr int kQB = 32;
constexpr float kScale = 0.04419417382415922f;   // 1/sqrt(512)
constexpr float kNegInf = -3.0e38f;

typedef __attribute__((ext_vector_type(8))) short short8;   // 8 bf16
typedef __attribute__((ext_vector_type(4))) short short4v;  // 4 bf16 (8 B)
typedef __attribute__((ext_vector_type(4))) float f32x4;
typedef __attribute__((ext_vector_type(4))) int   i32x4;

__device__ inline uint16_t f2bf(float f) {       // f32 -> bf16 bits, RNE
    union { float f; uint32_t u; } x; x.f = f;
    uint32_t r = x.u + 0x7fffu + ((x.u >> 16) & 1u);
    return (uint16_t)(r >> 16);
}
__device__ inline float bf2f(uint16_t h) {
    union { uint32_t u; float f; } x; x.u = ((uint32_t)h) << 16;
    return x.f;
}

__global__ __launch_bounds__(512, 4)             // cap VGPR<=128 -> 2 WG/CU
void sdpa_kernel(const float* __restrict__ Q, const float* __restrict__ K,
                 const float* __restrict__ V, const int* __restrict__ M,
                 float* __restrict__ Og, float* __restrict__ Ag) {
    // P: scores->p, bf16, row-major [32][1024], elem index XOR-swizzled by (row&7)<<3
    __shared__ uint16_t P_lds[kQB * kS];         // 65536 B
    // Vt: transposed V chunk (KC=64), bf16 [d=64][stride 72] -> conflict-free b128 reads
    __shared__ uint16_t Vt[kD * 72];             // 9216 B
    __shared__ float inv_lds[kQB];               // 128 B   (total 74880 B -> 2 WG/CU)

    // XCD swizzle: 512 consecutive logical WGs (16 bh) per XCD -> K/V L2-resident
    const int logical = (blockIdx.x & 7) * 512 + (blockIdx.x >> 3);
    const int bh = logical >> 5;
    const int q0 = (logical & 31) * kQB;

    const int tid  = threadIdx.x;
    const int wave = tid >> 6;
    const int lane = tid & 63;
    const int l16  = lane & 15;
    const int lg   = lane >> 4;

    const float* qb = Q + (size_t)bh * kS * kD;
    const float* kb = K + (size_t)bh * kS * kD;
    const float* vb = V + (size_t)bh * kS * kD;

    // ---- Q fragments: A[row=l16][k=lg*8+j], vectorized f32x4 loads ----
    short8 afr[2][2];
    #pragma unroll
    for (int m = 0; m < 2; ++m)
    #pragma unroll
    for (int ks = 0; ks < 2; ++ks) {
        const float* p = qb + (size_t)(q0 + m * 16 + l16) * kD + ks * 32 + lg * 8;
        f32x4 lo = *(const f32x4*)p;
        f32x4 hi = *(const f32x4*)(p + 4);
        short8 t;
        #pragma unroll
        for (int j = 0; j < 4; ++j) { t[j] = (short)f2bf(lo[j]); t[j + 4] = (short)f2bf(hi[j]); }
        afr[m][ks] = t;
    }

    // ---- Phase 1: raw QK^T -> P_lds (bf16, swizzled); wave owns 128-col slice ----
    const int n0 = wave * 128;
    for (int nt = 0; nt < 8; ++nt) {
        const int nb = n0 + nt * 16;
        short8 bfr[2];
        #pragma unroll
        for (int ks = 0; ks < 2; ++ks) {
            const float* p = kb + (size_t)(nb + l16) * kD + ks * 32 + lg * 8;
            f32x4 lo = *(const f32x4*)p;
            f32x4 hi = *(const f32x4*)(p + 4);
            short8 t;
            #pragma unroll
            for (int j = 0; j < 4; ++j) { t[j] = (short)f2bf(lo[j]); t[j + 4] = (short)f2bf(hi[j]); }
            bfr[ks] = t;
        }
        #pragma unroll
        for (int m = 0; m < 2; ++m) {
            f32x4 acc = {0.f, 0.f, 0.f, 0.f};
            acc = __builtin_amdgcn_mfma_f32_16x16x32_bf16(afr[m][0], bfr[0], acc, 0, 0, 0);
            acc = __builtin_amdgcn_mfma_f32_16x16x32_bf16(afr[m][1], bfr[1], acc, 0, 0, 0);
            #pragma unroll
            for (int r = 0; r < 4; ++r) {        // C/D: col=lane&15, row=(lane>>4)*4+r
                const int rr = m * 16 + lg * 4 + r;
                const int e  = (rr * kS + nb + l16) ^ ((rr & 7) << 3);
                P_lds[e] = f2bf(acc[r]);
            }
        }
    }
    __syncthreads();

    // ---- early V prefetch for phase-3 chunk 0 (T14: issue-early, write-late) ----
    const int kp = tid >> 4;                     // 0..31 (k-pair)
    const int dq = tid & 15;                     // d-quad
    f32x4 vr0 = *(const f32x4*)(vb + (size_t)(2 * kp) * kD + dq * 4);
    f32x4 vr1 = *(const f32x4*)(vb + (size_t)(2 * kp + 1) * kD + dq * 4);

    // ---- Phase 2: mask+scale -> rowmax -> exp -> rowsum -> attn write ----
    {
        const int row = tid >> 4;                // 32 rows x 16 threads
        const int c0  = (tid & 15) * 4;
        const int swz = (row & 7) << 3;
        const int* mrow = M + ((size_t)bh * kS + q0 + row) * kS;
        uint16_t* prow = P_lds + row * kS;

        float mx = kNegInf;
        #pragma unroll
        for (int i = 0; i < 16; ++i) {
            const int c = c0 + i * 64;
            i32x4 mk = *(const i32x4*)(mrow + c);            // coalesced int4
            const int cc = c ^ swz;
            short4v s4 = *(const short4v*)(prow + cc);
            f32x4 e;
            e.x = mk.x ? kNegInf : bf2f((uint16_t)s4.x) * kScale;
            e.y = mk.y ? kNegInf : bf2f((uint16_t)s4.y) * kScale;
            e.z = mk.z ? kNegInf : bf2f((uint16_t)s4.z) * kScale;
            e.w = mk.w ? kNegInf : bf2f((uint16_t)s4.w) * kScale;
            short4v w4;
            w4.x = (short)f2bf(e.x); w4.y = (short)f2bf(e.y);
            w4.z = (short)f2bf(e.z); w4.w = (short)f2bf(e.w);
            *(short4v*)(prow + cc) = w4;
            mx = fmaxf(mx, fmaxf(fmaxf(e.x, e.y), fmaxf(e.z, e.w)));
        }
        #pragma unroll
        for (int o = 8; o; o >>= 1) mx = fmaxf(mx, __shfl_xor(mx, o));

        float sum = 0.f;
        #pragma unroll
        for (int i = 0; i < 16; ++i) {
            const int cc = (c0 + i * 64) ^ swz;
            short4v s4 = *(const short4v*)(prow + cc);
            f32x4 p;
            p.x = __expf(bf2f((uint16_t)s4.x) - mx);
            p.y = __expf(bf2f((uint16_t)s4.y) - mx);
            p.z = __expf(bf2f((uint16_t)s4.z) - mx);
            p.w = __expf(bf2f((uint16_t)s4.w) - mx);
            short4v w4;
            w4.x = (short)f2bf(p.x); w4.y = (short)f2bf(p.y);
            w4.z = (short)f2bf(p.z); w4.w = (short)f2bf(p.w);
            *(short4v*)(prow + cc) = w4;                     // unnormalized p, bf16
            sum += (p.x + p.y) + (p.z + p.w);
        }
        #pragma unroll
        for (int o = 8; o; o >>= 1) sum += __shfl_xor(sum, o);
        const float inv = 1.0f / sum;
        if ((tid & 15) == 0) inv_lds[row] = inv;

        float* arow = Ag + ((size_t)bh * kS + q0 + row) * kS;
        #pragma unroll
        for (int i = 0; i < 16; ++i) {
            const int c = c0 + i * 64;
            short4v p4 = *(const short4v*)(prow + (c ^ swz));
            f32x4 a;
            a.x = bf2f((uint16_t)p4.x) * inv;
            a.y = bf2f((uint16_t)p4.y) * inv;
            a.z = bf2f((uint16_t)p4.z) * inv;
            a.w = bf2f((uint16_t)p4.w) * inv;
            *(f32x4*)(arow + c) = a;                         // coalesced f32x4 store
        }
    }
    __syncthreads();

    // ---- Phase 3: O = P @ V via LDS-staged Vt chunks; inv folded into epilogue ----
    {
        const int m  = wave >> 2;                // 0..1
        const int d0 = (wave & 3) * 16;          // 0..48
        const int arowbase = (m * 16 + l16) * kS;
        const int aswz = (l16 & 7) << 3;
        f32x4 acc = {0.f, 0.f, 0.f, 0.f};

        for (int ck = 0; ck < 16; ++ck) {        // KC=64 rows per chunk
            if (ck) __syncthreads();             // prev compute done, Vt free
            #pragma unroll
            for (int i = 0; i < 4; ++i) {        // transpose-stage: Vt[d][2kp..2kp+1]
                uint32_t pk = (uint32_t)f2bf(vr0[i]) | ((uint32_t)f2bf(vr1[i]) << 16);
                *(uint32_t*)(Vt + (dq * 4 + i) * 72 + 2 * kp) = pk;
            }
            __syncthreads();                     // stage visible
            if (ck < 15) {                       // prefetch next chunk before compute
                const float* s = vb + (size_t)((ck + 1) * 64 + 2 * kp) * kD + dq * 4;
                vr0 = *(const f32x4*)s;
                vr1 = *(const f32x4*)(s + kD);
            }
            #pragma unroll
            for (int ks = 0; ks < 2; ++ks) {
                const int eA = (arowbase + ck * 64 + ks * 32 + lg * 8) ^ aswz;
                short8 a = *(const short8*)(P_lds + eA);               // conflict-free b128
                short8 b = *(const short8*)(Vt + (d0 + l16) * 72 + ks * 32 + lg * 8);
                acc = __builtin_amdgcn_mfma_f32_16x16x32_bf16(a, b, acc, 0, 0, 0);
            }
        }

        f32x4 invv = *(const f32x4*)(inv_lds + m * 16 + lg * 4);
        float* orow = Og + ((size_t)bh * kS + q0 + m * 16 + lg * 4) * kD + d0 + l16;
        #pragma unroll
        for (int r = 0; r < 4; ++r) orow[(size_t)r * kD] = acc[r] * invv[r];
    }
}

} // namespace

extern "C" void kernel_launch(void* const* d_in, const int* in_sizes, int n_in,
                              void* d_out, int out_size, void* d_ws, size_t ws_size,
                              hipStream_t stream) {
    const float* q = (const float*)d_in[0];
    const float* k = (const float*)d_in[1];
    const float* v = (const float*)d_in[2];
    const int*   m = (const int*)d_in[3];
    float* og = (float*)d_out;
    float* ag = og + (size_t)kBH * kS * kD;      // outputs concatenated: O then attn
    sdpa_kernel<<<dim3(kBH * (kS / kQB)), dim3(512), 0, stream>>>(q, k, v, m, og, ag);
}

// Round 4
// 361.958 us; speedup vs baseline: 1.7854x; 1.0839x over previous
//
#include <hip/hip_runtime.h>
#include <stdint.h>

namespace {

constexpr int kBH = 128;
constexpr int kS  = 1024;
constexpr int kD  = 64;
constexpr int kQB = 32;
constexpr float kScale = 0.04419417382415922f;   // 1/sqrt(512)
constexpr float kNegInf = -3.0e38f;

typedef __attribute__((ext_vector_type(8))) short short8;   // 8 bf16
typedef __attribute__((ext_vector_type(4))) short short4v;  // 4 bf16 (8 B)
typedef __attribute__((ext_vector_type(4))) float f32x4;
typedef __attribute__((ext_vector_type(4))) int   i32x4;
typedef __attribute__((ext_vector_type(2))) unsigned int u32x2;

__device__ inline uint16_t f2bf(float f) {       // f32 -> bf16 bits, RNE
    union { float f; uint32_t u; } x; x.f = f;
    uint32_t r = x.u + 0x7fffu + ((x.u >> 16) & 1u);
    return (uint16_t)(r >> 16);
}
__device__ inline float bf2f(uint16_t h) {
    union { uint32_t u; float f; } x; x.u = ((uint32_t)h) << 16;
    return x.f;
}
__device__ inline uint32_t pkbf(float lo, float hi) {
    return (uint32_t)f2bf(lo) | ((uint32_t)f2bf(hi) << 16);
}

// ---- prep 1: K f32 [bh][k][d] -> bf16 same layout ----
__global__ __launch_bounds__(256)
void conv_k_kernel(const float* __restrict__ K, uint16_t* __restrict__ Kb) {
    const size_t base = ((size_t)blockIdx.x * 256 + threadIdx.x) * 8;
    f32x4 a = *(const f32x4*)(K + base);
    f32x4 b = *(const f32x4*)(K + base + 4);
    short8 t;
    #pragma unroll
    for (int j = 0; j < 4; ++j) { t[j] = (short)f2bf(a[j]); t[j + 4] = (short)f2bf(b[j]); }
    *(short8*)(Kb + base) = t;
}

// ---- prep 2: V f32 [bh][k][d] -> bf16 transposed Vt [bh][d][k] ----
__global__ __launch_bounds__(256)
void transp_v_kernel(const float* __restrict__ V, uint16_t* __restrict__ Vt) {
    __shared__ float t[64][65];
    const int bh = blockIdx.x >> 4;
    const int kb = blockIdx.x & 15;               // 64-row k block
    const int tid = threadIdx.x;
    const float* vb = V + ((size_t)bh * kS + kb * 64) * kD;
    #pragma unroll
    for (int rep = 0; rep < 4; ++rep) {
        const int k = (tid >> 4) + rep * 16;
        const int d4 = (tid & 15) * 4;
        f32x4 x = *(const f32x4*)(vb + (size_t)k * kD + d4);
        #pragma unroll
        for (int j = 0; j < 4; ++j) t[k][d4 + j] = x[j];
    }
    __syncthreads();
    const int d  = tid >> 2;
    const int kq = (tid & 3) * 16;
    short8 o0, o1;
    #pragma unroll
    for (int j = 0; j < 8; ++j) {
        o0[j] = (short)f2bf(t[kq + j][d]);
        o1[j] = (short)f2bf(t[kq + 8 + j][d]);
    }
    uint16_t* orow = Vt + ((size_t)bh * kD + d) * kS + kb * 64 + kq;
    *(short8*)(orow)     = o0;
    *(short8*)(orow + 8) = o1;
}

__global__ __launch_bounds__(512, 4)             // cap VGPR<=128 -> 2 WG/CU
void sdpa_kernel(const float* __restrict__ Q, const uint16_t* __restrict__ Kb,
                 const uint16_t* __restrict__ Vt, const int* __restrict__ M,
                 float* __restrict__ Og, float* __restrict__ Ag) {
    // P: bf16 [32][1024]; element index XOR-swizzled by (row&7)<<3 (b64/b128 safe)
    __shared__ uint16_t P_lds[kQB * kS];         // 65536 B
    __shared__ float inv_lds[kQB];               // -> 2 WG/CU

    // XCD swizzle: 512 consecutive logical WGs (16 bh) per XCD -> Kb/Vt L2-resident
    const int logical = (blockIdx.x & 7) * 512 + (blockIdx.x >> 3);
    const int bh = logical >> 5;
    const int q0 = (logical & 31) * kQB;

    const int tid  = threadIdx.x;
    const int wave = tid >> 6;
    const int lane = tid & 63;
    const int l16  = lane & 15;
    const int lg   = lane >> 4;

    const float*    qb  = Q  + (size_t)bh * kS * kD;
    const uint16_t* kbb = Kb + (size_t)bh * kS * kD;

    // ---- Q fragments: B-operand B[k=lg*8+j][col=l16 -> q-row] ----
    short8 afr[2][2];
    #pragma unroll
    for (int m = 0; m < 2; ++m)
    #pragma unroll
    for (int ks = 0; ks < 2; ++ks) {
        const float* p = qb + (size_t)(q0 + m * 16 + l16) * kD + ks * 32 + lg * 8;
        f32x4 lo = *(const f32x4*)p;
        f32x4 hi = *(const f32x4*)(p + 4);
        short8 t;
        #pragma unroll
        for (int j = 0; j < 4; ++j) { t[j] = (short)f2bf(lo[j]); t[j + 4] = (short)f2bf(hi[j]); }
        afr[m][ks] = t;
    }

    // ---- Phase 1: S^T = K·Q^T -> lane holds 4 consecutive cols of one q-row ----
    const int n0 = wave * 128;
    #pragma unroll 2
    for (int nt = 0; nt < 8; ++nt) {
        const int nb = n0 + nt * 16;
        const uint16_t* krow = kbb + (size_t)(nb + l16) * kD + lg * 8;
        short8 kf0 = *(const short8*)(krow);
        short8 kf1 = *(const short8*)(krow + 32);
        #pragma unroll
        for (int m = 0; m < 2; ++m) {
            f32x4 acc = {0.f, 0.f, 0.f, 0.f};
            acc = __builtin_amdgcn_mfma_f32_16x16x32_bf16(kf0, afr[m][0], acc, 0, 0, 0);
            acc = __builtin_amdgcn_mfma_f32_16x16x32_bf16(kf1, afr[m][1], acc, 0, 0, 0);
            // lane: S[q=q0+m*16+l16][n=nb+lg*4+r], r=0..3 -> one packed b64 store
            const int rowq = m * 16 + l16;
            const int e = rowq * kS + ((nb + lg * 4) ^ ((rowq & 7) << 3));
            u32x2 w; w.x = pkbf(acc[0], acc[1]); w.y = pkbf(acc[2], acc[3]);
            *(u32x2*)(P_lds + e) = w;
        }
    }
    __syncthreads();

    // ---- Phase 2 (single pass): mask+scale -> max -> exp -> sum -> stores ----
    #pragma unroll
    for (int round = 0; round < 2; ++round) {
        const int row = round * 16 + (tid >> 5);  // 16 rows x 32 threads
        const int c0  = (tid & 31) * 4;
        const int swz = (row & 7) << 3;
        const int* mrow = M + ((size_t)bh * kS + q0 + row) * kS;
        uint16_t* prow = P_lds + row * kS;

        float e[32];
        float mx = kNegInf;
        #pragma unroll
        for (int i = 0; i < 8; ++i) {
            const int c = c0 + i * 128;
            i32x4 mk = *(const i32x4*)(mrow + c);            // coalesced 16B
            short4v s4 = *(const short4v*)(prow + (c ^ swz));
            float v0 = mk.x ? kNegInf : bf2f((uint16_t)s4.x) * kScale;
            float v1 = mk.y ? kNegInf : bf2f((uint16_t)s4.y) * kScale;
            float v2 = mk.z ? kNegInf : bf2f((uint16_t)s4.z) * kScale;
            float v3 = mk.w ? kNegInf : bf2f((uint16_t)s4.w) * kScale;
            e[4 * i + 0] = v0; e[4 * i + 1] = v1; e[4 * i + 2] = v2; e[4 * i + 3] = v3;
            mx = fmaxf(mx, fmaxf(fmaxf(v0, v1), fmaxf(v2, v3)));
        }
        #pragma unroll
        for (int o = 16; o; o >>= 1) mx = fmaxf(mx, __shfl_xor(mx, o));

        float sum = 0.f;
        #pragma unroll
        for (int j = 0; j < 32; ++j) { float p = __expf(e[j] - mx); e[j] = p; sum += p; }
        #pragma unroll
        for (int o = 16; o; o >>= 1) sum += __shfl_xor(sum, o);
        const float inv = 1.0f / sum;
        if ((tid & 31) == 0) inv_lds[row] = inv;

        float* arow = Ag + ((size_t)bh * kS + q0 + row) * kS;
        #pragma unroll
        for (int i = 0; i < 8; ++i) {
            const int c = c0 + i * 128;
            u32x2 w;                                         // unnormalized p, bf16 -> LDS
            w.x = pkbf(e[4 * i + 0], e[4 * i + 1]);
            w.y = pkbf(e[4 * i + 2], e[4 * i + 3]);
            *(u32x2*)(prow + (c ^ swz)) = w;
            f32x4 a = { e[4 * i + 0] * inv, e[4 * i + 1] * inv,
                        e[4 * i + 2] * inv, e[4 * i + 3] * inv };
            *(f32x4*)(arow + c) = a;                         // coalesced f32 attn store
        }
    }
    __syncthreads();

    // ---- Phase 3: O = P @ V, zero barriers; Vt b128 from L2, P b128 from LDS ----
    {
        const int m  = wave >> 2;                // 0..1
        const int d0 = (wave & 3) * 16;          // 0..48
        const uint16_t* vtrow = Vt + ((size_t)bh * kD + d0 + l16) * kS + lg * 8;
        const int abase = (m * 16 + l16) * kS;
        const int aswz  = (l16 & 7) << 3;
        f32x4 acc0 = {0.f, 0.f, 0.f, 0.f};
        f32x4 acc1 = {0.f, 0.f, 0.f, 0.f};
        #pragma unroll
        for (int kk = 0; kk < 32; kk += 2) {
            short8 a0 = *(const short8*)(P_lds + abase + ((kk * 32 + lg * 8) ^ aswz));
            short8 b0 = *(const short8*)(vtrow + kk * 32);
            acc0 = __builtin_amdgcn_mfma_f32_16x16x32_bf16(a0, b0, acc0, 0, 0, 0);
            short8 a1 = *(const short8*)(P_lds + abase + (((kk + 1) * 32 + lg * 8) ^ aswz));
            short8 b1 = *(const short8*)(vtrow + (kk + 1) * 32);
            acc1 = __builtin_amdgcn_mfma_f32_16x16x32_bf16(a1, b1, acc1, 0, 0, 0);
        }
        f32x4 acc = acc0 + acc1;
        f32x4 invv = *(const f32x4*)(inv_lds + m * 16 + lg * 4);
        float* orow = Og + ((size_t)bh * kS + q0 + m * 16 + lg * 4) * kD + d0 + l16;
        #pragma unroll
        for (int r = 0; r < 4; ++r) orow[(size_t)r * kD] = acc[r] * invv[r];
    }
}

} // namespace

extern "C" void kernel_launch(void* const* d_in, const int* in_sizes, int n_in,
                              void* d_out, int out_size, void* d_ws, size_t ws_size,
                              hipStream_t stream) {
    const float* q = (const float*)d_in[0];
    const float* k = (const float*)d_in[1];
    const float* v = (const float*)d_in[2];
    const int*   m = (const int*)d_in[3];
    float* og = (float*)d_out;
    float* ag = og + (size_t)kBH * kS * kD;      // outputs concatenated: O then attn

    uint16_t* kb = (uint16_t*)d_ws;              // 16.78 MB bf16 K
    uint16_t* vt = kb + (size_t)kBH * kS * kD;   // 16.78 MB bf16 V^T [bh][d][k]

    conv_k_kernel<<<dim3(4096), dim3(256), 0, stream>>>(k, kb);
    transp_v_kernel<<<dim3(2048), dim3(256), 0, stream>>>(v, vt);
    sdpa_kernel<<<dim3(kBH * (kS / kQB)), dim3(512), 0, stream>>>(q, kb, vt, m, og, ag);
}